// Round 5
// baseline (5070.875 us; speedup 1.0000x reference)
//
#include <hip/hip_runtime.h>
#include <cstddef>
#include <cstdint>

// ---------------------------------------------------------------------------
// LSTM  B=64 T=512 I=H=1024
// Phase A: pack weights -> bf16 N-major transposes + bias concat
// Phase B: xproj[t][b][4H] = bf16( x @ [wii|wif|wig|wio] + b )   (MFMA GEMM)
// Phase C: persistent recurrence, 128 co-resident blocks x 8 H-cols each.
//   - halves the LLC h-broadcast (nblk*128KB/step) vs the 256-block version
//   - fence-free: h via write-through (sc1) stores + bypass (sc0 sc1) loads
//   - direct poll-all barrier (128 slots)
//   - inner loop: R2-proven single vmcnt(0) + direct wh LDS reads (no breg
//     double-buffer -> no spill-garbage hazard that NaN'd the R4 attempt)
// ---------------------------------------------------------------------------

typedef __bf16 bf16_t;
typedef __bf16 bf16x8 __attribute__((ext_vector_type(8)));
typedef __bf16 bf16x4 __attribute__((ext_vector_type(4)));
typedef __bf16 bf16x2 __attribute__((ext_vector_type(2)));
typedef float  f32x4  __attribute__((ext_vector_type(4)));
typedef float  f32x2  __attribute__((ext_vector_type(2)));

#define MFMA16(a, b, c) __builtin_amdgcn_mfma_f32_16x16x32_bf16((a), (b), (c), 0, 0, 0)

// ---- problem constants ----
#define BB   64          // batch
#define TT   512         // time steps
#define HH   1024        // hidden = input
#define G4H  4096        // 4*H
#define NBLK 128         // recurrent blocks (8 H-cols each)

// ---- workspace layout (bytes) ----
#define XPROJ_OFF  0ull                               // [T][B][4H] bf16 = 256 MB
#define WX_OFF     268435456ull                       // Wx^T [4096][1024] bf16 = 8 MB
#define WH_OFF     (WX_OFF + 8388608ull)              // Wh^T [4096][1024] bf16 = 8 MB
#define BC_OFF     (WH_OFF + 8388608ull)              // bias concat f32[4096]
#define HB_OFF     (BC_OFF + 16384ull)                // h double buffer 2*64*1024 bf16
#define BAR_OFF    (HB_OFF + 262144ull)               // arrival array [NBLK] u32

__device__ __forceinline__ float fsig(float x) {
    return 1.0f / (1.0f + __expf(-x));
}
__device__ __forceinline__ float ftanh(float x) {
    return 1.0f - 2.0f / (__expf(2.0f * x) + 1.0f);
}

// ---------------------------------------------------------------------------
// Transpose-pack: src fp32 [1024 k][1024 h]  ->  dst bf16 [h][k] (N-major).
// ---------------------------------------------------------------------------
__global__ void transpose_pack(const float* __restrict__ s0, const float* __restrict__ s1,
                               const float* __restrict__ s2, const float* __restrict__ s3,
                               const float* __restrict__ s4, const float* __restrict__ s5,
                               const float* __restrict__ s6, const float* __restrict__ s7,
                               bf16_t* __restrict__ wxt, bf16_t* __restrict__ wht) {
    __shared__ float tile[64][65];
    const int z = blockIdx.z;
    const float* src = (z == 0) ? s0 : (z == 1) ? s1 : (z == 2) ? s2 : (z == 3) ? s3
                      : (z == 4) ? s4 : (z == 5) ? s5 : (z == 6) ? s6 : s7;
    bf16_t* dst = ((z < 4) ? wxt : wht) + (size_t)(z & 3) * 1024 * 1024;
    const int k0 = blockIdx.x * 64, h0 = blockIdx.y * 64;
    const int t = threadIdx.x;
#pragma unroll
    for (int i = 0; i < 16; ++i) {
        int kk = (t >> 6) * 16 + i, hh = t & 63;
        tile[kk][hh] = src[(size_t)(k0 + kk) * 1024 + h0 + hh];
    }
    __syncthreads();
#pragma unroll
    for (int i = 0; i < 16; ++i) {
        int hh = (t >> 6) * 16 + i, kk = t & 63;
        dst[(size_t)(h0 + hh) * 1024 + k0 + kk] = (bf16_t)tile[kk][hh];
    }
}

__global__ void pack_bias(const float* __restrict__ bi, const float* __restrict__ bf_,
                          const float* __restrict__ bg, const float* __restrict__ bo,
                          float* __restrict__ bc) {
    int n = blockIdx.x * 256 + threadIdx.x;   // 0..4095
    int g = n >> 10, h = n & 1023;
    const float* s = (g == 0) ? bi : (g == 1) ? bf_ : (g == 2) ? bg : bo;
    bc[n] = s[h];
}

// ---------------------------------------------------------------------------
// Phase B GEMM: xproj[(t*64+b)][n] = sum_k x[b*512+t][k] * WxT[n][k] + bc[n]
// ---------------------------------------------------------------------------
__global__ __launch_bounds__(256, 2) void gemm_xproj(
    const float* __restrict__ x, const bf16_t* __restrict__ wx,
    const float* __restrict__ bc, bf16_t* __restrict__ xp) {
    __shared__ bf16_t Als[128][72];
    __shared__ bf16_t Bls[128][72];
    const int tid = threadIdx.x;
    const int n0 = blockIdx.x * 128, m0 = blockIdx.y * 128;
    const int lane = tid & 63, w = tid >> 6;
    const int wm = w >> 1, wn = w & 1;
    const int col = lane & 15, quad = lane >> 4;
    const int rowA = tid >> 4, ksegA = (tid & 15) * 4;
    const int rowB = tid >> 3, chunkB = tid & 7;
    f32x4 acc[4][4] = {};

    for (int kt = 0; kt < 16; ++kt) {
        const int k0 = kt * 64;
        __syncthreads();
#pragma unroll
        for (int i = 0; i < 8; ++i) {
            int r = rowA + i * 16;
            float4 v = *(const float4*)&x[(size_t)(m0 + r) * 1024 + k0 + ksegA];
            bf16x4 pv = { (bf16_t)v.x, (bf16_t)v.y, (bf16_t)v.z, (bf16_t)v.w };
            *(bf16x4*)&Als[r][ksegA] = pv;
        }
#pragma unroll
        for (int i = 0; i < 4; ++i) {
            int r = rowB + i * 32;
            *(bf16x8*)&Bls[r][chunkB * 8] =
                *(const bf16x8*)&wx[(size_t)(n0 + r) * 1024 + k0 + chunkB * 8];
        }
        __syncthreads();
#pragma unroll
        for (int kq = 0; kq < 64; kq += 32) {
            bf16x8 a[4], b[4];
#pragma unroll
            for (int s = 0; s < 4; ++s) {
                a[s] = *(const bf16x8*)&Als[wm * 64 + s * 16 + col][kq + quad * 8];
                b[s] = *(const bf16x8*)&Bls[wn * 64 + s * 16 + col][kq + quad * 8];
            }
#pragma unroll
            for (int sm = 0; sm < 4; ++sm)
#pragma unroll
                for (int sn = 0; sn < 4; ++sn)
                    acc[sm][sn] = MFMA16(a[sm], b[sn], acc[sm][sn]);
        }
    }
#pragma unroll
    for (int sm = 0; sm < 4; ++sm) {
        int mbase = m0 + wm * 64 + sm * 16 + quad * 4;
#pragma unroll
        for (int sn = 0; sn < 4; ++sn) {
            int n = n0 + wn * 64 + sn * 16 + col;
            float bias = bc[n];
#pragma unroll
            for (int reg = 0; reg < 4; ++reg) {
                int mm = mbase + reg;
                int b = mm >> 9, t = mm & 511;
                xp[(size_t)((t << 6) + b) * 4096 + n] = (bf16_t)(acc[sm][sn][reg] + bias);
            }
        }
    }
}

// ---------------------------------------------------------------------------
// Phase C: persistent recurrence, fence-free, 128 blocks x 8 H-cols.
// Block bid owns H-cols [bid*8, bid*8+8) -> 32 gate cols (i,f,g,o x 8),
// LDS rows r = g*8+c  <->  WhT row g*1024 + bid*8 + c.
// Per wave: M=16 batch rows (regs, LLC bypass) x N=32 (LDS), K=1024.
// ---------------------------------------------------------------------------
__global__ __launch_bounds__(256, 1) void lstm_rec(
    const bf16_t* __restrict__ xproj, const bf16_t* __restrict__ whc,
    bf16_t* __restrict__ hbuf, float* __restrict__ out,
    unsigned int* __restrict__ bar) {
    __shared__ bf16_t wh[32][1032];   // 66 KB; row stride 2064B
    __shared__ float  gl[64][36];     // gate scratch, cols [0,32) used
    const int tid = threadIdx.x;
    const int bid = blockIdx.x;

    // stage Wh slice: row r <- WhT[(r>>3)*1024 + bid*8 + (r&7)][:]
    {
        int r = tid >> 3, seg = tid & 7;
        const bf16_t* src = whc + (size_t)((r >> 3) * 1024 + bid * 8 + (r & 7)) * 1024;
#pragma unroll
        for (int j = 0; j < 16; ++j) {
            int e = seg * 128 + j * 8;
            *(bf16x8*)&wh[r][e] = *(const bf16x8*)&src[e];
        }
    }
    __syncthreads();

    const int w = tid >> 6, lane = tid & 63;
    const int col = lane & 15, quad = lane >> 4;
    const int rowA = w * 16 + col;        // A-operand batch row
    const int bb0  = w * 16 + quad * 4;   // C-layout batch row base
    const int b2 = tid >> 2;              // activation batch (0..63)
    const int c2 = (tid & 3) * 2;         // activation col pair base (0,2,4,6)
    const int hcol = bid * 8 + c2;

    float cs0 = 0.0f, cs1 = 0.0f;         // two c-states per thread
    float* hseq = out;                          // [64][512][1024]
    float* hT = out + (size_t)BB * TT * HH;     // [64][1024]
    float* cT = hT + BB * HH;                   // [64][1024]

    // xproj prefetch: 4 dwords (one per gate), 2 bf16 each. t=0 here.
    unsigned xq[4];
#pragma unroll
    for (int g = 0; g < 4; ++g)
        xq[g] = *(const unsigned*)&xproj[(size_t)b2 * 4096 + g * 1024 + hcol];

    for (int t = 0; t < TT; ++t) {
        const bf16_t* hprev = hbuf + (size_t)(t & 1) * (BB * HH);
        bf16_t* hnext = hbuf + (size_t)((t + 1) & 1) * (BB * HH);

        // --- issue all 32 LLC-bypass h loads (sc0 sc1) ---
        const bf16_t* hbase = hprev + (size_t)rowA * 1024 + quad * 8;
        bf16x8 af[32];
#define LDH(i, o) asm volatile("global_load_dwordx4 %0, %1, off offset:" o " sc0 sc1" \
                               : "=v"(af[i]) : "v"(hbase))
        LDH(0, "0");     LDH(1, "64");    LDH(2, "128");   LDH(3, "192");
        LDH(4, "256");   LDH(5, "320");   LDH(6, "384");   LDH(7, "448");
        LDH(8, "512");   LDH(9, "576");   LDH(10, "640");  LDH(11, "704");
        LDH(12, "768");  LDH(13, "832");  LDH(14, "896");  LDH(15, "960");
        LDH(16, "1024"); LDH(17, "1088"); LDH(18, "1152"); LDH(19, "1216");
        LDH(20, "1280"); LDH(21, "1344"); LDH(22, "1408"); LDH(23, "1472");
        LDH(24, "1536"); LDH(25, "1600"); LDH(26, "1664"); LDH(27, "1728");
        LDH(28, "1792"); LDH(29, "1856"); LDH(30, "1920"); LDH(31, "1984");
#undef LDH
        asm volatile("s_waitcnt vmcnt(0)" ::: "memory");
        __builtin_amdgcn_sched_barrier(0);

        // --- GEMM: two 16-col tiles, wh read directly from LDS (R2 pattern) ---
        f32x4 acc0 = {0.f, 0.f, 0.f, 0.f};
        f32x4 acc1 = {0.f, 0.f, 0.f, 0.f};
#pragma unroll
        for (int kq = 0; kq < 32; ++kq) {
            bf16x8 b0 = *(const bf16x8*)&wh[col][kq * 32 + quad * 8];
            bf16x8 b1 = *(const bf16x8*)&wh[16 + col][kq * 32 + quad * 8];
            acc0 = MFMA16(af[kq], b0, acc0);
            acc1 = MFMA16(af[kq], b1, acc1);
        }

        // gates -> LDS. Rows [16w,16w+16) written AND read by wave w only.
#pragma unroll
        for (int reg = 0; reg < 4; ++reg) {
            gl[bb0 + reg][col]      = acc0[reg];
            gl[bb0 + reg][16 + col] = acc1[reg];
        }

        // --- activations: batch b2, H-cols hcol, hcol+1 ---
        float a0l = gl[b2][0 * 8 + c2]     + __uint_as_float(xq[0] << 16);
        float a0h = gl[b2][0 * 8 + c2 + 1] + __uint_as_float(xq[0] & 0xffff0000u);
        float a1l = gl[b2][1 * 8 + c2]     + __uint_as_float(xq[1] << 16);
        float a1h = gl[b2][1 * 8 + c2 + 1] + __uint_as_float(xq[1] & 0xffff0000u);
        float a2l = gl[b2][2 * 8 + c2]     + __uint_as_float(xq[2] << 16);
        float a2h = gl[b2][2 * 8 + c2 + 1] + __uint_as_float(xq[2] & 0xffff0000u);
        float a3l = gl[b2][3 * 8 + c2]     + __uint_as_float(xq[3] << 16);
        float a3h = gl[b2][3 * 8 + c2 + 1] + __uint_as_float(xq[3] & 0xffff0000u);
        cs0 = fsig(a1l) * cs0 + fsig(a0l) * ftanh(a2l);
        cs1 = fsig(a1h) * cs1 + fsig(a0h) * ftanh(a2h);
        float hv0 = fsig(a3l) * ftanh(cs0);
        float hv1 = fsig(a3h) * ftanh(cs1);

        // hseq: f32x2 nontemporal (32B contiguous per 4-lane group)
        f32x2 hv2 = { hv0, hv1 };
        __builtin_nontemporal_store(hv2, (f32x2*)&hseq[(size_t)b2 * (TT * HH) + t * HH + hcol]);

        // h publish: pack 2 bf16 -> u32, write-through sc1 store (to LLC)
        bf16x2 hb2 = { (bf16_t)hv0, (bf16_t)hv1 };
        unsigned hpk = __builtin_bit_cast(unsigned, hb2);
        __hip_atomic_store((unsigned*)(hnext + (size_t)b2 * HH + hcol), hpk,
                           __ATOMIC_RELAXED, __HIP_MEMORY_SCOPE_AGENT);

        if (t == TT - 1) {
            __builtin_nontemporal_store(hv2, (f32x2*)&hT[(size_t)b2 * HH + hcol]);
            f32x2 cv2 = { cs0, cs1 };
            __builtin_nontemporal_store(cv2, (f32x2*)&cT[(size_t)b2 * HH + hcol]);
            break;                                    // no barrier after last step
        }

        __syncthreads();   // all waves drain vmcnt before s_barrier -> h at LLC

        const unsigned tgt = (unsigned)(t + 1);
        const size_t xoff = (size_t)((t + 1) * 64 + b2) * 4096 + bid * 8 + c2;
        if (w == 0) {
            asm volatile("s_waitcnt vmcnt(0)" ::: "memory");   // belt & braces
            if (lane == 0)
                __hip_atomic_store(&bar[bid], tgt, __ATOMIC_RELAXED,
                                   __HIP_MEMORY_SCOPE_AGENT);
            asm volatile("" ::: "memory");
            // prefetch next xproj before polling
#pragma unroll
            for (int g = 0; g < 4; ++g)
                xq[g] = *(const unsigned*)&xproj[xoff + (size_t)g * 1024];
            // direct poll-all: lane l watches bar[l], bar[64+l]
            for (;;) {
                unsigned v0 = __hip_atomic_load(bar + lane, __ATOMIC_RELAXED,
                                                __HIP_MEMORY_SCOPE_AGENT);
                unsigned v1 = __hip_atomic_load(bar + 64 + lane, __ATOMIC_RELAXED,
                                                __HIP_MEMORY_SCOPE_AGENT);
                if (__all((v0 >= tgt) & (v1 >= tgt))) break;
                __builtin_amdgcn_s_sleep(1);
            }
        } else {
            // waves 1..3: prefetch next xproj while wave 0 polls
#pragma unroll
            for (int g = 0; g < 4; ++g)
                xq[g] = *(const unsigned*)&xproj[xoff + (size_t)g * 1024];
        }
        __syncthreads();   // releases waves 1..3; orders next h loads after barrier
    }
}

// ---------------------------------------------------------------------------
extern "C" void kernel_launch(void* const* d_in, const int* in_sizes, int n_in,
                              void* d_out, int out_size, void* d_ws, size_t ws_size,
                              hipStream_t stream) {
    (void)in_sizes; (void)n_in; (void)out_size; (void)ws_size;
    const float* x   = (const float*)d_in[0];
    const float* wii = (const float*)d_in[1];
    const float* whi = (const float*)d_in[2];
    const float* bi  = (const float*)d_in[3];
    const float* wif = (const float*)d_in[4];
    const float* whf = (const float*)d_in[5];
    const float* bfb = (const float*)d_in[6];
    const float* wig = (const float*)d_in[7];
    const float* whg = (const float*)d_in[8];
    const float* bg  = (const float*)d_in[9];
    const float* wio = (const float*)d_in[10];
    const float* who = (const float*)d_in[11];
    const float* bo  = (const float*)d_in[12];

    char* ws = (char*)d_ws;
    bf16_t*   xp   = (bf16_t*)(ws + XPROJ_OFF);
    bf16_t*   wxt  = (bf16_t*)(ws + WX_OFF);
    bf16_t*   wht  = (bf16_t*)(ws + WH_OFF);
    float*    bc   = (float*)(ws + BC_OFF);
    bf16_t*   hbuf = (bf16_t*)(ws + HB_OFF);
    unsigned* bar  = (unsigned*)(ws + BAR_OFF);

    // zero h double-buffer + arrival array (contiguous region)
    (void)hipMemsetAsync(hbuf, 0, 262144 + 4096, stream);

    transpose_pack<<<dim3(16, 16, 8), 256, 0, stream>>>(wii, wif, wig, wio,
                                                        whi, whf, whg, who, wxt, wht);
    pack_bias<<<16, 256, 0, stream>>>(bi, bfb, bg, bo, bc);
    gemm_xproj<<<dim3(32, 256), 256, 0, stream>>>(x, wxt, bc, xp);
    lstm_rec<<<NBLK, 256, 0, stream>>>(xp, wht, hbuf, (float*)d_out, bar);
}

// Round 6
// 3893.243 us; speedup vs baseline: 1.3025x; 1.3025x over previous
//
#include <hip/hip_runtime.h>
#include <cstddef>
#include <cstdint>

// ---------------------------------------------------------------------------
// LSTM  B=64 T=512 I=H=1024
// Phase A: pack weights -> bf16 gate-INTERLEAVED transposes (n' = h*4+gate)
// Phase B: xproj GEMM, epilogue writes [t][bid][b][32] (coalesced 16B reads
//          per recurrence thread; kills the 5x HBM over-fetch)
// Phase C: persistent recurrence, 128 blocks x 8 H-cols, fence-free sync.
//   - chunked counted-vmcnt h loads (<=64 VGPRs in flight -> no spill)
//   - k-major wh LDS layout (conflict-free B reads)
//   - publish-first step tail: h-store -> vmcnt(0) -> barrier -> flag;
//     hseq NT store + xproj prefetch issued under the poll window
// ---------------------------------------------------------------------------

typedef __bf16 bf16_t;
typedef __bf16 bf16x8 __attribute__((ext_vector_type(8)));
typedef __bf16 bf16x4 __attribute__((ext_vector_type(4)));
typedef __bf16 bf16x2 __attribute__((ext_vector_type(2)));
typedef float  f32x4  __attribute__((ext_vector_type(4)));
typedef float  f32x2  __attribute__((ext_vector_type(2)));

#define MFMA16(a, b, c) __builtin_amdgcn_mfma_f32_16x16x32_bf16((a), (b), (c), 0, 0, 0)

// ---- problem constants ----
#define BB   64          // batch
#define TT   512         // time steps
#define HH   1024        // hidden = input
#define NBLK 128         // recurrent blocks (8 H-cols each)

// ---- workspace layout (bytes) ----
#define XPROJ_OFF  0ull                               // [T][128][64][32] bf16 = 256 MB
#define WX_OFF     268435456ull                       // Wx^T interleaved [4096][1024] bf16
#define WH_OFF     (WX_OFF + 8388608ull)              // Wh^T interleaved [4096][1024] bf16
#define BC_OFF     (WH_OFF + 8388608ull)              // bias interleaved f32[4096]
#define HB_OFF     (BC_OFF + 16384ull)                // h double buffer 2*64*1024 bf16
#define BAR_OFF    (HB_OFF + 262144ull)               // arrival array [NBLK] u32

__device__ __forceinline__ float fsig(float x) {
    return 1.0f / (1.0f + __expf(-x));
}
__device__ __forceinline__ float ftanh(float x) {
    return 1.0f - 2.0f / (__expf(2.0f * x) + 1.0f);
}

// ---------------------------------------------------------------------------
// Transpose-pack: src fp32 [1024 k][1024 h] -> dst bf16 row n' = h*4 + gate.
// ---------------------------------------------------------------------------
__global__ void transpose_pack(const float* __restrict__ s0, const float* __restrict__ s1,
                               const float* __restrict__ s2, const float* __restrict__ s3,
                               const float* __restrict__ s4, const float* __restrict__ s5,
                               const float* __restrict__ s6, const float* __restrict__ s7,
                               bf16_t* __restrict__ wxt, bf16_t* __restrict__ wht) {
    __shared__ float tile[64][65];
    const int z = blockIdx.z;
    const float* src = (z == 0) ? s0 : (z == 1) ? s1 : (z == 2) ? s2 : (z == 3) ? s3
                      : (z == 4) ? s4 : (z == 5) ? s5 : (z == 6) ? s6 : s7;
    bf16_t* dst = (z < 4) ? wxt : wht;
    const int gate = z & 3;
    const int k0 = blockIdx.x * 64, h0 = blockIdx.y * 64;
    const int t = threadIdx.x;
#pragma unroll
    for (int i = 0; i < 16; ++i) {
        int kk = (t >> 6) * 16 + i, hh = t & 63;
        tile[kk][hh] = src[(size_t)(k0 + kk) * 1024 + h0 + hh];
    }
    __syncthreads();
#pragma unroll
    for (int i = 0; i < 16; ++i) {
        int hh = (t >> 6) * 16 + i, kk = t & 63;
        dst[(size_t)((h0 + hh) * 4 + gate) * 1024 + k0 + kk] = (bf16_t)tile[kk][hh];
    }
}

__global__ void pack_bias(const float* __restrict__ bi, const float* __restrict__ bf_,
                          const float* __restrict__ bg, const float* __restrict__ bo,
                          float* __restrict__ bc) {
    int n = blockIdx.x * 256 + threadIdx.x;   // 0..4095 = h*4 + gate
    int g = n & 3, h = n >> 2;
    const float* s = (g == 0) ? bi : (g == 1) ? bf_ : (g == 2) ? bg : bo;
    bc[n] = s[h];
}

// ---------------------------------------------------------------------------
// Phase B GEMM over interleaved n'. Epilogue -> xp[t][n'>>5][b][n'&31].
// ---------------------------------------------------------------------------
__global__ __launch_bounds__(256, 2) void gemm_xproj(
    const float* __restrict__ x, const bf16_t* __restrict__ wx,
    const float* __restrict__ bc, bf16_t* __restrict__ xp) {
    __shared__ bf16_t Als[128][72];
    __shared__ bf16_t Bls[128][72];
    const int tid = threadIdx.x;
    const int n0 = blockIdx.x * 128, m0 = blockIdx.y * 128;
    const int lane = tid & 63, w = tid >> 6;
    const int wm = w >> 1, wn = w & 1;
    const int col = lane & 15, quad = lane >> 4;
    const int rowA = tid >> 4, ksegA = (tid & 15) * 4;
    const int rowB = tid >> 3, chunkB = tid & 7;
    f32x4 acc[4][4] = {};

    for (int kt = 0; kt < 16; ++kt) {
        const int k0 = kt * 64;
        __syncthreads();
#pragma unroll
        for (int i = 0; i < 8; ++i) {
            int r = rowA + i * 16;
            float4 v = *(const float4*)&x[(size_t)(m0 + r) * 1024 + k0 + ksegA];
            bf16x4 pv = { (bf16_t)v.x, (bf16_t)v.y, (bf16_t)v.z, (bf16_t)v.w };
            *(bf16x4*)&Als[r][ksegA] = pv;
        }
#pragma unroll
        for (int i = 0; i < 4; ++i) {
            int r = rowB + i * 32;
            *(bf16x8*)&Bls[r][chunkB * 8] =
                *(const bf16x8*)&wx[(size_t)(n0 + r) * 1024 + k0 + chunkB * 8];
        }
        __syncthreads();
#pragma unroll
        for (int kq = 0; kq < 64; kq += 32) {
            bf16x8 a[4], b[4];
#pragma unroll
            for (int s = 0; s < 4; ++s) {
                a[s] = *(const bf16x8*)&Als[wm * 64 + s * 16 + col][kq + quad * 8];
                b[s] = *(const bf16x8*)&Bls[wn * 64 + s * 16 + col][kq + quad * 8];
            }
#pragma unroll
            for (int sm = 0; sm < 4; ++sm)
#pragma unroll
                for (int sn = 0; sn < 4; ++sn)
                    acc[sm][sn] = MFMA16(a[sm], b[sn], acc[sm][sn]);
        }
    }
#pragma unroll
    for (int sm = 0; sm < 4; ++sm) {
        int mbase = m0 + wm * 64 + sm * 16 + quad * 4;
#pragma unroll
        for (int sn = 0; sn < 4; ++sn) {
            int n = n0 + wn * 64 + sn * 16 + col;
            float bias = bc[n];
            int bidr = n >> 5, off = n & 31;
#pragma unroll
            for (int reg = 0; reg < 4; ++reg) {
                int mm = mbase + reg;
                int b = mm >> 9, t = mm & 511;
                xp[((size_t)(t * 128 + bidr) * 64 + b) * 32 + off] =
                    (bf16_t)(acc[sm][sn][reg] + bias);
            }
        }
    }
}

// ---------------------------------------------------------------------------
// Phase C: persistent recurrence, fence-free, 128 blocks x 8 H-cols.
// Block bid owns n' in [bid*32, bid*32+32) (8 H-cols x 4 gates interleaved).
// wh2 k-major: wh2[k>>3][n'off][k&7] -> conflict-free ds_read_b128.
// ---------------------------------------------------------------------------
__global__ __launch_bounds__(256, 1) void lstm_rec(
    const bf16_t* __restrict__ xproj, const bf16_t* __restrict__ whc,
    bf16_t* __restrict__ hbuf, float* __restrict__ out,
    unsigned int* __restrict__ bar) {
    __shared__ bf16_t wh2[128][32][8];   // 64 KB, k-major
    __shared__ float  gl[64][37];        // gate scratch (stride 37 dw)
    const int tid = threadIdx.x;
    const int bid = blockIdx.x;

    // stage Wh slice: n'off r = tid>>3 (0..31), k-chunk seg = tid&7
    {
        int r = tid >> 3, seg = tid & 7;
        const bf16_t* src = whc + (size_t)(bid * 32 + r) * 1024;
#pragma unroll
        for (int j = 0; j < 16; ++j) {
            int k = seg * 128 + j * 8;
            *(bf16x8*)&wh2[k >> 3][r][0] = *(const bf16x8*)&src[k];
        }
    }
    __syncthreads();

    const int w = tid >> 6, lane = tid & 63;
    const int col = lane & 15, quad = lane >> 4;
    const int rowA = w * 16 + col;        // A-operand batch row
    const int bb0  = w * 16 + quad * 4;   // C-layout batch row base
    const int b2 = tid >> 2;              // activation batch (0..63)
    const int c2 = (tid & 3) * 2;         // activation col pair base (0,2,4,6)
    const int hcol = bid * 8 + c2;

    float cs0 = 0.0f, cs1 = 0.0f;
    float* hseq = out;                          // [64][512][1024]
    float* hT = out + (size_t)BB * TT * HH;     // [64][1024]
    float* cT = hT + BB * HH;                   // [64][1024]

    // xproj prefetch: ONE coalesced 16B load per thread (8 bf16 = 2 cols x 4 gates)
    bf16x8 xq = *(const bf16x8*)&xproj[((size_t)bid * 64 + b2) * 32 + c2 * 4];

    for (int t = 0; t < TT; ++t) {
        const bf16_t* hprev = hbuf + (size_t)(t & 1) * (BB * HH);
        bf16_t* hnext = hbuf + (size_t)((t + 1) & 1) * (BB * HH);

        const bf16_t* hbase = hprev + (size_t)rowA * 1024 + quad * 8;
        f32x4 acc0 = {0.f, 0.f, 0.f, 0.f};
        f32x4 acc1 = {0.f, 0.f, 0.f, 0.f};
        bf16x8 af0[8], af1[8];   // two 8-chunk buffers: <=64 VGPRs in flight

#define LDH(arr, i, o) asm volatile("global_load_dwordx4 %0, %1, off offset:" o " sc0 sc1" \
                                    : "=v"(arr[i]) : "v"(hbase))
#define MFMA8(buf, kqb)                                                        \
    _Pragma("unroll")                                                          \
    for (int j = 0; j < 8; ++j) {                                              \
        bf16x8 b0 = *(const bf16x8*)&wh2[((kqb) + j) * 4 + quad][col][0];      \
        bf16x8 b1 = *(const bf16x8*)&wh2[((kqb) + j) * 4 + quad][16 + col][0]; \
        acc0 = MFMA16(buf[j], b0, acc0);                                       \
        acc1 = MFMA16(buf[j], b1, acc1);                                       \
    }

        // chunk0 (kq 0-7) + chunk1 (kq 8-15)
        LDH(af0, 0, "0");    LDH(af0, 1, "64");   LDH(af0, 2, "128");  LDH(af0, 3, "192");
        LDH(af0, 4, "256");  LDH(af0, 5, "320");  LDH(af0, 6, "384");  LDH(af0, 7, "448");
        LDH(af1, 0, "512");  LDH(af1, 1, "576");  LDH(af1, 2, "640");  LDH(af1, 3, "704");
        LDH(af1, 4, "768");  LDH(af1, 5, "832");  LDH(af1, 6, "896");  LDH(af1, 7, "960");
        asm volatile("s_waitcnt vmcnt(8)" ::: "memory");   // chunk0 ready
        __builtin_amdgcn_sched_barrier(0);
        MFMA8(af0, 0)
        LDH(af0, 0, "1024"); LDH(af0, 1, "1088"); LDH(af0, 2, "1152"); LDH(af0, 3, "1216");
        LDH(af0, 4, "1280"); LDH(af0, 5, "1344"); LDH(af0, 6, "1408"); LDH(af0, 7, "1472");
        asm volatile("s_waitcnt vmcnt(8)" ::: "memory");   // chunk1 ready
        __builtin_amdgcn_sched_barrier(0);
        MFMA8(af1, 8)
        LDH(af1, 0, "1536"); LDH(af1, 1, "1600"); LDH(af1, 2, "1664"); LDH(af1, 3, "1728");
        LDH(af1, 4, "1792"); LDH(af1, 5, "1856"); LDH(af1, 6, "1920"); LDH(af1, 7, "1984");
        asm volatile("s_waitcnt vmcnt(8)" ::: "memory");   // chunk2 ready
        __builtin_amdgcn_sched_barrier(0);
        MFMA8(af0, 16)
        asm volatile("s_waitcnt vmcnt(0)" ::: "memory");   // chunk3 ready
        __builtin_amdgcn_sched_barrier(0);
        MFMA8(af1, 24)
#undef MFMA8
#undef LDH

        // gates -> LDS. Rows [16w,16w+16) written AND read by wave w only.
#pragma unroll
        for (int reg = 0; reg < 4; ++reg) {
            gl[bb0 + reg][col]      = acc0[reg];
            gl[bb0 + reg][16 + col] = acc1[reg];
        }

        // --- activations: batch b2, interleaved gate cols c2*4 .. c2*4+7 ---
        float il  = gl[b2][c2 * 4 + 0] + (float)xq[0];
        float fl_ = gl[b2][c2 * 4 + 1] + (float)xq[1];
        float ggl = gl[b2][c2 * 4 + 2] + (float)xq[2];
        float ol  = gl[b2][c2 * 4 + 3] + (float)xq[3];
        float ih  = gl[b2][c2 * 4 + 4] + (float)xq[4];
        float fh  = gl[b2][c2 * 4 + 5] + (float)xq[5];
        float gh  = gl[b2][c2 * 4 + 6] + (float)xq[6];
        float oh  = gl[b2][c2 * 4 + 7] + (float)xq[7];
        cs0 = fsig(fl_) * cs0 + fsig(il) * ftanh(ggl);
        cs1 = fsig(fh) * cs1 + fsig(ih) * ftanh(gh);
        float hv0 = fsig(ol) * ftanh(cs0);
        float hv1 = fsig(oh) * ftanh(cs1);
        f32x2 hv2 = { hv0, hv1 };

        if (t == TT - 1) {
            __builtin_nontemporal_store(hv2, (f32x2*)&hseq[(size_t)b2 * (TT * HH) + t * HH + hcol]);
            __builtin_nontemporal_store(hv2, (f32x2*)&hT[(size_t)b2 * HH + hcol]);
            f32x2 cv2 = { cs0, cs1 };
            __builtin_nontemporal_store(cv2, (f32x2*)&cT[(size_t)b2 * HH + hcol]);
            break;
        }

        // --- publish-first tail: h -> LLC, ack, block-arrive, then slow ops ---
        bf16x2 hb2 = { (bf16_t)hv0, (bf16_t)hv1 };
        unsigned hpk = __builtin_bit_cast(unsigned, hb2);
        __hip_atomic_store((unsigned*)(hnext + (size_t)b2 * HH + hcol), hpk,
                           __ATOMIC_RELAXED, __HIP_MEMORY_SCOPE_AGENT);
        asm volatile("s_waitcnt vmcnt(0)" ::: "memory");   // only the h store pending
        __syncthreads();                                    // all 4 waves' h at LLC

        const unsigned tgt = (unsigned)(t + 1);
        if (w == 0 && lane == 0)
            __hip_atomic_store(&bar[bid], tgt, __ATOMIC_RELAXED,
                               __HIP_MEMORY_SCOPE_AGENT);
        // long-latency, non-critical ops under the poll window:
        __builtin_nontemporal_store(hv2, (f32x2*)&hseq[(size_t)b2 * (TT * HH) + t * HH + hcol]);
        xq = *(const bf16x8*)&xproj[((size_t)((t + 1) * 128 + bid) * 64 + b2) * 32 + c2 * 4];

        if (w == 0) {
            // direct poll-all: lane l watches bar[l], bar[64+l]
            for (;;) {
                unsigned v0 = __hip_atomic_load(bar + lane, __ATOMIC_RELAXED,
                                                __HIP_MEMORY_SCOPE_AGENT);
                unsigned v1 = __hip_atomic_load(bar + 64 + lane, __ATOMIC_RELAXED,
                                                __HIP_MEMORY_SCOPE_AGENT);
                if (__all((v0 >= tgt) & (v1 >= tgt))) break;
                __builtin_amdgcn_s_sleep(1);
            }
        }
        __syncthreads();   // releases waves 1..3; orders next h loads after barrier
    }
}

// ---------------------------------------------------------------------------
extern "C" void kernel_launch(void* const* d_in, const int* in_sizes, int n_in,
                              void* d_out, int out_size, void* d_ws, size_t ws_size,
                              hipStream_t stream) {
    (void)in_sizes; (void)n_in; (void)out_size; (void)ws_size;
    const float* x   = (const float*)d_in[0];
    const float* wii = (const float*)d_in[1];
    const float* whi = (const float*)d_in[2];
    const float* bi  = (const float*)d_in[3];
    const float* wif = (const float*)d_in[4];
    const float* whf = (const float*)d_in[5];
    const float* bfb = (const float*)d_in[6];
    const float* wig = (const float*)d_in[7];
    const float* whg = (const float*)d_in[8];
    const float* bg  = (const float*)d_in[9];
    const float* wio = (const float*)d_in[10];
    const float* who = (const float*)d_in[11];
    const float* bo  = (const float*)d_in[12];

    char* ws = (char*)d_ws;
    bf16_t*   xp   = (bf16_t*)(ws + XPROJ_OFF);
    bf16_t*   wxt  = (bf16_t*)(ws + WX_OFF);
    bf16_t*   wht  = (bf16_t*)(ws + WH_OFF);
    float*    bc   = (float*)(ws + BC_OFF);
    bf16_t*   hbuf = (bf16_t*)(ws + HB_OFF);
    unsigned* bar  = (unsigned*)(ws + BAR_OFF);

    // zero h double-buffer + arrival array (contiguous region)
    (void)hipMemsetAsync(hbuf, 0, 262144 + 4096, stream);

    transpose_pack<<<dim3(16, 16, 8), 256, 0, stream>>>(wii, wif, wig, wio,
                                                        whi, whf, whg, who, wxt, wht);
    pack_bias<<<16, 256, 0, stream>>>(bi, bfb, bg, bo, bc);
    gemm_xproj<<<dim3(32, 256), 256, 0, stream>>>(x, wxt, bc, xp);
    lstm_rec<<<NBLK, 256, 0, stream>>>(xp, wht, hbuf, (float*)d_out, bar);
}